// Round 3
// baseline (296.927 us; speedup 1.0000x reference)
//
#include <hip/hip_runtime.h>
#include <stdint.h>

typedef uint16_t u16;
typedef __attribute__((ext_vector_type(4))) float f32x4;
typedef __attribute__((ext_vector_type(4))) unsigned short us4;
typedef __attribute__((ext_vector_type(8))) unsigned short us8;

#define NB   16
#define NN   512
#define FF   625      // H*W
#define FH   937      // int(625*1.5)
#define ROWS 8192     // NB*NN
#define KS1  1280     // [X(625) pad->640 | t1(625) pad->640]
#define KS2  1920     // [h(937) pad->960 | t2(937) pad->960]
#define NP1  1024     // Fh padded to 128
#define NP2  640      // F padded to 128
#define F4   160      // 640/4 float4 slots per padded X row

using frag_ab = __attribute__((ext_vector_type(8))) short;  // 8 bf16
using frag_cd = __attribute__((ext_vector_type(4))) float;  // 4 fp32

__device__ __forceinline__ u16 f32_bf16(float f) {
  union { float f; uint32_t u; } x; x.f = f;
  uint32_t r = x.u + 0x7fffu + ((x.u >> 16) & 1u);   // RNE
  return (u16)(r >> 16);
}
__device__ __forceinline__ float bf16_f32(u16 u) {
  union { uint32_t u; float f; } x; x.u = ((uint32_t)u) << 16;
  return x.f;
}
__device__ __forceinline__ void gload_lds16(const void* g, void* l) {
  __builtin_amdgcn_global_load_lds((__attribute__((address_space(1))) void*)g,
                                   (__attribute__((address_space(3))) void*)l,
                                   16, 0, 0);
}

// ---------------------------------------------------------------------------
// pad_x: x4 [ROWS][625] fp32 -> Xpad [ROWS][160] f32x4 (zero pad) and
// Xcat bf16 cols 0..639.
// ---------------------------------------------------------------------------
__global__ __launch_bounds__(256) void pad_x(const float* __restrict__ x4,
                                             f32x4* __restrict__ Xpad,
                                             u16* __restrict__ Xcat) {
  const int idx = blockIdx.x * 256 + threadIdx.x;
  if (idx >= ROWS * F4) return;
  const int row = idx / F4;
  const int k4 = idx - row * F4;
  f32x4 v;
  us4 o;
  #pragma unroll
  for (int t = 0; t < 4; ++t) {
    const int f = k4 * 4 + t;
    float x = (f < FF) ? x4[(size_t)row * FF + f] : 0.f;
    v[t] = x;
    o[t] = f32_bf16(x);
  }
  Xpad[idx] = v;
  *(us4*)(Xcat + (size_t)row * KS1 + k4 * 4) = o;
}

// ---------------------------------------------------------------------------
// build_graph v3: 4 candidates per wave-iteration. All 12 f32x4 loads issued
// up front (MLP), one packed-f32x4 butterfly per 4 candidates (amortizes the
// 6-step serial shfl chain), register accumulation of accepted rows.
// ---------------------------------------------------------------------------
__global__ __launch_bounds__(256) void build_graph(
    const f32x4* __restrict__ Xpad,  // [ROWS][160]
    const float* __restrict__ att,   // [ROWS]
    u16* __restrict__ Xcat,          // [ROWS][KS1] bf16 (t1 half written here)
    u16* __restrict__ nbr,           // [ROWS][512]
    int* __restrict__ degbuf,
    float* __restrict__ invbuf)
{
  __shared__ float att_sh[512];
  __shared__ f32x4 Xi4[F4];
  __shared__ u16 cand[512];
  __shared__ u16 accj[512];
  __shared__ f32x4 wsum[4][F4];
  __shared__ int ncand, nacc;

  const int tid = threadIdx.x;
  const int row = blockIdx.x;
  const int b = row >> 9;
  const int i = row & 511;
  const f32x4* Xb4 = Xpad + (size_t)b * NN * F4;

  att_sh[tid]       = att[b * NN + tid];
  att_sh[tid + 256] = att[b * NN + tid + 256];
  if (tid < F4) Xi4[tid] = Xb4[(size_t)i * F4 + tid];
  if (tid == 0) { ncand = 0; nacc = 0; }
  __syncthreads();

  const float ai = att_sh[i];
  for (int j = tid; j < NN; j += 256) {
    if (j != i && fabsf(ai - att_sh[j]) <= 0.05f) {
      int p = atomicAdd(&ncand, 1);
      cand[p] = (u16)j;
    }
  }
  __syncthreads();

  const int lane = tid & 63;
  const int wave = tid >> 6;
  const int nc = ncand;

  const f32x4 zero = {0.f, 0.f, 0.f, 0.f};
  const f32x4 a0 = Xi4[lane];
  const f32x4 a1 = Xi4[64 + lane];
  const f32x4 a2 = (lane < 32) ? Xi4[128 + lane] : zero;
  f32x4 s0 = zero, s1 = zero, s2 = zero;

  for (int cc = wave * 4; cc < nc; cc += 16) {
    f32x4 x0[4], x1[4], x2[4];
    #pragma unroll
    for (int k = 0; k < 4; ++k) {
      const int idx = cc + k;
      const int j = cand[idx < nc ? idx : nc - 1];
      const f32x4* Xj = Xb4 + (size_t)j * F4;
      x0[k] = Xj[lane];
      x1[k] = Xj[64 + lane];
      x2[k] = (lane < 32) ? Xj[128 + lane] : zero;
    }
    f32x4 pv;
    #pragma unroll
    for (int k = 0; k < 4; ++k) {
      const f32x4 d0 = a0 - x0[k], d1 = a1 - x1[k], d2 = a2 - x2[k];
      float p = 0.f;
      #pragma unroll
      for (int t = 0; t < 4; ++t)
        p += fabsf(d0[t]) + fabsf(d1[t]) + fabsf(d2[t]);
      pv[k] = p;
    }
    #pragma unroll
    for (int off = 32; off; off >>= 1) {
      f32x4 o;
      o[0] = __shfl_xor(pv[0], off, 64);
      o[1] = __shfl_xor(pv[1], off, 64);
      o[2] = __shfl_xor(pv[2], off, 64);
      o[3] = __shfl_xor(pv[3], off, 64);
      pv += o;
    }
    #pragma unroll
    for (int k = 0; k < 4; ++k) {
      if (cc + k < nc && pv[k] <= 180.0f) {    // wave-uniform
        s0 += x0[k]; s1 += x1[k]; s2 += x2[k];
        if (lane == 0) { int q = atomicAdd(&nacc, 1); accj[q] = cand[cc + k]; }
      }
    }
  }
  wsum[wave][lane] = s0;
  wsum[wave][64 + lane] = s1;
  if (lane < 32) wsum[wave][128 + lane] = s2;
  __syncthreads();

  const int na = nacc;
  const float inv = 1.0f / (float)(na + 1);
  for (int c = tid; c < na; c += 256) nbr[(size_t)row * 512 + c] = accj[c];
  if (tid == 0) { degbuf[row] = na; invbuf[row] = inv; }

  for (int k = tid; k < F4; k += 256) {
    f32x4 t = Xi4[k];
    #pragma unroll
    for (int w = 0; w < 4; ++w) t += wsum[w][k];
    us4 o;
    #pragma unroll
    for (int s = 0; s < 4; ++s) o[s] = f32_bf16(t[s] * inv);
    *(us4*)(Xcat + (size_t)row * KS1 + 640 + k * 4) = o;
  }
}

// ---------------------------------------------------------------------------
// gather2 (unchanged): t2 = (h_i + sum_j h_j) * inv, us8 loads, 2-group split.
// ---------------------------------------------------------------------------
__global__ __launch_bounds__(256) void gather2(
    u16* __restrict__ hcat,          // [ROWS][KS2] bf16
    const u16* __restrict__ nbr,
    const int* __restrict__ degbuf,
    const float* __restrict__ invbuf)
{
  __shared__ u16 accj[512];
  __shared__ float hsum[2][960];

  const int tid = threadIdx.x;
  const int row = blockIdx.x;
  const int b = row >> 9;
  const int na = degbuf[row];
  const float inv = invbuf[row];
  for (int c = tid; c < na; c += 256) accj[c] = nbr[(size_t)row * 512 + c];
  __syncthreads();

  const int g = tid >> 7;
  const int slot = tid & 127;
  const u16* hbat = hcat + (size_t)b * NN * KS2;

  float s[8] = {0,0,0,0,0,0,0,0};
  if (slot < 120) {
    for (int c = g; c < na; c += 2) {
      const us8 hv = *(const us8*)(hbat + (size_t)accj[c] * KS2 + slot * 8);
      #pragma unroll
      for (int t = 0; t < 8; ++t) s[t] += bf16_f32(hv[t]);
    }
    #pragma unroll
    for (int t = 0; t < 8; ++t) hsum[g][slot * 8 + t] = s[t];
  }
  __syncthreads();

  if (tid < 23) hcat[(size_t)row * KS2 + FH + tid] = 0;

  const u16* hrow = hcat + (size_t)row * KS2;
  for (int k = tid; k < 120; k += 256) {
    const us8 hv = *(const us8*)(hrow + k * 8);
    us8 o;
    #pragma unroll
    for (int t = 0; t < 8; ++t) {
      const int col = k * 8 + t;
      float v = (bf16_f32(hv[t]) + hsum[0][col] + hsum[1][col]) * inv;
      o[t] = (col < FH) ? f32_bf16(v) : (u16)0;
    }
    *(us8*)(hcat + (size_t)row * KS2 + 960 + k * 8) = o;
  }
}

// ---------------------------------------------------------------------------
// Weight converters (unchanged).
// ---------------------------------------------------------------------------
__global__ __launch_bounds__(256) void convert_w1(const float* __restrict__ W1,
                                                  u16* __restrict__ Wt) {
  __shared__ float tile[32][33];
  const int kt = blockIdx.x, nt = blockIdx.y;
  const int tx = threadIdx.x & 31, ty = threadIdx.x >> 5;
  #pragma unroll
  for (int r = 0; r < 4; ++r) {
    int k = kt * 32 + ty + r * 8;
    int n = nt * 32 + tx;
    float v = 0.f;
    int c = -1, kk = 0;
    if (k < 625) { c = 0; kk = k; }
    else if (k >= 640 && k < 1265) { c = 1; kk = k - 640; }
    if (c >= 0 && n < FH) v = W1[((size_t)c * 625 + kk) * FH + n];
    tile[ty + r * 8][tx] = v;
  }
  __syncthreads();
  #pragma unroll
  for (int r = 0; r < 4; ++r) {
    int n = nt * 32 + ty + r * 8;
    int k = kt * 32 + tx;
    Wt[(size_t)n * KS1 + k] = f32_bf16(tile[tx][ty + r * 8]);
  }
}

__global__ __launch_bounds__(256) void convert_w2(const float* __restrict__ W2,
                                                  u16* __restrict__ Wt) {
  __shared__ float tile[32][33];
  const int kt = blockIdx.x, nt = blockIdx.y;
  const int tx = threadIdx.x & 31, ty = threadIdx.x >> 5;
  #pragma unroll
  for (int r = 0; r < 4; ++r) {
    int k = kt * 32 + ty + r * 8;
    int n = nt * 32 + tx;
    float v = 0.f;
    int c = -1, kk = 0;
    if (k < 937) { c = 0; kk = k; }
    else if (k >= 960 && k < 1897) { c = 1; kk = k - 960; }
    if (c >= 0 && n < FF) v = W2[((size_t)c * 937 + kk) * FF + n];
    tile[ty + r * 8][tx] = v;
  }
  __syncthreads();
  #pragma unroll
  for (int r = 0; r < 4; ++r) {
    int n = nt * 32 + ty + r * 8;
    int k = kt * 32 + tx;
    Wt[(size_t)n * KS2 + k] = f32_bf16(tile[tx][ty + r * 8]);
  }
}

// ---------------------------------------------------------------------------
// gemm64: 64M x 128N block tile, 4 waves, each wave 64Mx32N (4x2 of 16x16x32).
// A [M][KS], Bt [Npad][KS]. Doubles grid size vs 128x128 (tail/occupancy).
// ---------------------------------------------------------------------------
template <int KS, int NREAL, int LDC, bool OUT_BF16>
__global__ __launch_bounds__(256) void gemm64(
    const u16* __restrict__ A, const u16* __restrict__ Bt,
    const float* __restrict__ bias, void* __restrict__ C)
{
  __shared__ __align__(16) u16 Ash[64 * 32];    // 4 KB
  __shared__ __align__(16) u16 Bsh[128 * 32];   // 8 KB

  const int tid  = threadIdx.x;
  const int lane = tid & 63;
  const int wave = tid >> 6;
  const int q = lane >> 4, l16 = lane & 15;
  const int m0 = blockIdx.x * 64;
  const int n0 = blockIdx.y * 128;

  // staging: A one round (idx=tid), B two rounds (idx=tid, 256+tid)
  const u16* pa  = A  + (size_t)(m0 + (tid >> 2)) * KS + (tid & 3) * 8;
  const u16* pb0 = Bt + (size_t)(n0 + (tid >> 2)) * KS + (tid & 3) * 8;
  const u16* pb1 = Bt + (size_t)(n0 + 64 + (tid >> 2)) * KS + (tid & 3) * 8;
  const int wbase = (tid & 192) * 8;            // wave-uniform (u16 units)
  u16* la  = &Ash[wbase];
  u16* lb0 = &Bsh[wbase];
  u16* lb1 = &Bsh[2048 + wbase];

  const frag_ab* fA[4]; const frag_ab* fB[2];
  #pragma unroll
  for (int mi = 0; mi < 4; ++mi)
    fA[mi] = (const frag_ab*)&Ash[(mi * 16 + l16) * 32 + q * 8];
  #pragma unroll
  for (int ni = 0; ni < 2; ++ni)
    fB[ni] = (const frag_ab*)&Bsh[(wave * 32 + ni * 16 + l16) * 32 + q * 8];

  frag_cd acc[4][2] = {};

  constexpr int KT = KS / 32;
  for (int kt = 0; kt < KT; ++kt) {
    __syncthreads();
    gload_lds16(pa, la);
    gload_lds16(pb0, lb0); gload_lds16(pb1, lb1);
    pa += 32; pb0 += 32; pb1 += 32;
    __syncthreads();

    frag_ab av[4], bv[2];
    #pragma unroll
    for (int mi = 0; mi < 4; ++mi) av[mi] = *fA[mi];
    #pragma unroll
    for (int ni = 0; ni < 2; ++ni) bv[ni] = *fB[ni];
    #pragma unroll
    for (int mi = 0; mi < 4; ++mi)
      #pragma unroll
      for (int ni = 0; ni < 2; ++ni)
        acc[mi][ni] = __builtin_amdgcn_mfma_f32_16x16x32_bf16(
            av[mi], bv[ni], acc[mi][ni], 0, 0, 0);
  }

  #pragma unroll
  for (int ni = 0; ni < 2; ++ni) {
    const int col = n0 + wave * 32 + ni * 16 + l16;
    const bool ok = (col < NREAL);
    const float bvv = ok ? bias[col] : 0.f;
    #pragma unroll
    for (int mi = 0; mi < 4; ++mi) {
      #pragma unroll
      for (int r = 0; r < 4; ++r) {
        const int rowg = m0 + mi * 16 + q * 4 + r;
        float v = acc[mi][ni][r] + bvv;
        v = fmaxf(v, 0.f);
        if (ok) {
          if (OUT_BF16)
            ((u16*)C)[(size_t)rowg * LDC + col] = f32_bf16(v);
          else
            ((float*)C)[(size_t)rowg * LDC + col] = v;
        }
      }
    }
  }
}

// ---------------------------------------------------------------------------
extern "C" void kernel_launch(void* const* d_in, const int* in_sizes, int n_in,
                              void* d_out, int out_size, void* d_ws, size_t ws_size,
                              hipStream_t stream) {
  const float* x4  = (const float*)d_in[0];
  const float* att = (const float*)d_in[1];
  const float* W1  = (const float*)d_in[2];
  const float* b1  = (const float*)d_in[3];
  const float* W2  = (const float*)d_in[4];
  const float* b2  = (const float*)d_in[5];
  float* out = (float*)d_out;

  char* ws = (char*)d_ws;
  f32x4* Xpad = (f32x4*)ws; ws += (size_t)ROWS * F4 * 16;
  u16* Xcat = (u16*)ws;  ws += (size_t)ROWS * KS1 * 2;
  u16* hcat = (u16*)ws;  ws += (size_t)ROWS * KS2 * 2;
  u16* W1t  = (u16*)ws;  ws += (size_t)NP1 * KS1 * 2;
  u16* W2t  = (u16*)ws;  ws += (size_t)NP2 * KS2 * 2;
  u16* nbr  = (u16*)ws;  ws += (size_t)ROWS * 512 * 2;
  int*   deg = (int*)ws;   ws += (size_t)ROWS * 4;
  float* inv = (float*)ws; ws += (size_t)ROWS * 4;

  convert_w1<<<dim3(KS1 / 32, NP1 / 32), 256, 0, stream>>>(W1, W1t);
  convert_w2<<<dim3(KS2 / 32, NP2 / 32), 256, 0, stream>>>(W2, W2t);
  pad_x<<<dim3((ROWS * F4 + 255) / 256), 256, 0, stream>>>(x4, Xpad, Xcat);
  build_graph<<<dim3(ROWS), 256, 0, stream>>>(Xpad, att, Xcat, nbr, deg, inv);
  gemm64<KS1, FH, KS2, true><<<dim3(ROWS / 64, NP1 / 128), 256, 0, stream>>>(
      Xcat, W1t, b1, (void*)hcat);
  gather2<<<dim3(ROWS), 256, 0, stream>>>(hcat, nbr, deg, inv);
  gemm64<KS2, FF, FF, false><<<dim3(ROWS / 64, NP2 / 128), 256, 0, stream>>>(
      hcat, W2t, b2, (void*)out);
}

// Round 4
// 258.628 us; speedup vs baseline: 1.1481x; 1.1481x over previous
//
#include <hip/hip_runtime.h>
#include <stdint.h>

typedef uint16_t u16;
typedef __attribute__((ext_vector_type(4))) float f32x4;
typedef __attribute__((ext_vector_type(4))) unsigned short us4;
typedef __attribute__((ext_vector_type(8))) unsigned short us8;

#define NB   16
#define NN   512
#define FF   625      // H*W
#define FH   937      // int(625*1.5)
#define ROWS 8192     // NB*NN
#define KS1  1280     // [X(625) pad->640 | t1(625) pad->640]
#define KS2  1920     // [h(937) pad->960 | t2(937) pad->960]
#define NP1  1024     // Fh padded to 128
#define NP2  640      // F padded to 128
#define F4   160      // 640/4 float4 slots per padded X row

using frag_ab = __attribute__((ext_vector_type(8))) short;  // 8 bf16
using frag_cd = __attribute__((ext_vector_type(4))) float;  // 4 fp32

__device__ __forceinline__ u16 f32_bf16(float f) {
  union { float f; uint32_t u; } x; x.f = f;
  uint32_t r = x.u + 0x7fffu + ((x.u >> 16) & 1u);   // RNE
  return (u16)(r >> 16);
}
__device__ __forceinline__ float bf16_f32(u16 u) {
  union { uint32_t u; float f; } x; x.u = ((uint32_t)u) << 16;
  return x.f;
}
__device__ __forceinline__ void gload_lds16(const void* g, void* l) {
  __builtin_amdgcn_global_load_lds((__attribute__((address_space(1))) void*)g,
                                   (__attribute__((address_space(3))) void*)l,
                                   16, 0, 0);
}
// XCD-aware row swizzle: 8192 blocks -> XCD k handles rows [k*1024, k*1024+1024)
// = batches 2k,2k+1, so each XCD's L2 holds only its 2 batches' working set.
__device__ __forceinline__ int swiz_row(int blk) {
  return ((blk & 7) << 10) | (blk >> 3);
}

// ---------------------------------------------------------------------------
// pad_x: x4 [ROWS][625] fp32 -> Xpad [ROWS][160] f32x4 (zero pad) and
// Xcat bf16 cols 0..639.
// ---------------------------------------------------------------------------
__global__ __launch_bounds__(256) void pad_x(const float* __restrict__ x4,
                                             f32x4* __restrict__ Xpad,
                                             u16* __restrict__ Xcat) {
  const int idx = blockIdx.x * 256 + threadIdx.x;
  if (idx >= ROWS * F4) return;
  const int row = idx / F4;
  const int k4 = idx - row * F4;
  f32x4 v;
  us4 o;
  #pragma unroll
  for (int t = 0; t < 4; ++t) {
    const int f = k4 * 4 + t;
    float x = (f < FF) ? x4[(size_t)row * FF + f] : 0.f;
    v[t] = x;
    o[t] = f32_bf16(x);
  }
  Xpad[idx] = v;
  *(us4*)(Xcat + (size_t)row * KS1 + k4 * 4) = o;
}

// ---------------------------------------------------------------------------
// build_graph (v2 revert + XCD swizzle): per-row block. att filter ->
// candidates; one wave per candidate, float4 distance; accepted Xj accumulated
// in registers; combine wave partials in LDS; write t1 bf16 + nbr/deg/inv.
// VGPR ~36 -> 63% occupancy (v3's 4x unroll hit 64 VGPR / 38% occ: regressed).
// ---------------------------------------------------------------------------
__global__ __launch_bounds__(256) void build_graph(
    const f32x4* __restrict__ Xpad,  // [ROWS][160]
    const float* __restrict__ att,   // [ROWS]
    u16* __restrict__ Xcat,          // [ROWS][KS1] bf16 (t1 half written here)
    u16* __restrict__ nbr,           // [ROWS][512]
    int* __restrict__ degbuf,
    float* __restrict__ invbuf)
{
  __shared__ float att_sh[512];
  __shared__ f32x4 Xi4[F4];
  __shared__ u16 cand[512];
  __shared__ u16 accj[512];
  __shared__ f32x4 wsum[4][F4];
  __shared__ int ncand, nacc;

  const int tid = threadIdx.x;
  const int row = swiz_row(blockIdx.x);
  const int b = row >> 9;
  const int i = row & 511;
  const f32x4* Xb4 = Xpad + (size_t)b * NN * F4;

  att_sh[tid]       = att[b * NN + tid];
  att_sh[tid + 256] = att[b * NN + tid + 256];
  if (tid < F4) Xi4[tid] = Xb4[(size_t)i * F4 + tid];
  if (tid == 0) { ncand = 0; nacc = 0; }
  __syncthreads();

  const float ai = att_sh[i];
  for (int j = tid; j < NN; j += 256) {
    if (j != i && fabsf(ai - att_sh[j]) <= 0.05f) {
      int p = atomicAdd(&ncand, 1);
      cand[p] = (u16)j;
    }
  }
  __syncthreads();

  const int lane = tid & 63;
  const int wave = tid >> 6;
  const int nc = ncand;

  const f32x4 zero = {0.f, 0.f, 0.f, 0.f};
  f32x4 a0 = Xi4[lane];
  f32x4 a1 = Xi4[64 + lane];
  f32x4 a2 = (lane < 32) ? Xi4[128 + lane] : zero;
  f32x4 s0 = zero, s1 = zero, s2 = zero;

  for (int c = wave; c < nc; c += 4) {
    const int j = cand[c];
    const f32x4* Xj = Xb4 + (size_t)j * F4;
    f32x4 x0 = Xj[lane];
    f32x4 x1 = Xj[64 + lane];
    f32x4 x2 = (lane < 32) ? Xj[128 + lane] : zero;
    f32x4 d0 = a0 - x0, d1 = a1 - x1, d2 = a2 - x2;
    float p = 0.f;
    #pragma unroll
    for (int t = 0; t < 4; ++t)
      p += fabsf(d0[t]) + fabsf(d1[t]) + fabsf(d2[t]);
    #pragma unroll
    for (int off = 32; off; off >>= 1) p += __shfl_xor(p, off, 64);
    if (p <= 180.0f) {                       // wave-uniform after butterfly
      s0 += x0; s1 += x1; s2 += x2;
      if (lane == 0) { int q = atomicAdd(&nacc, 1); accj[q] = (u16)j; }
    }
  }
  wsum[wave][lane] = s0;
  wsum[wave][64 + lane] = s1;
  if (lane < 32) wsum[wave][128 + lane] = s2;
  __syncthreads();

  const int na = nacc;
  const float inv = 1.0f / (float)(na + 1);
  for (int c = tid; c < na; c += 256) nbr[(size_t)row * 512 + c] = accj[c];
  if (tid == 0) { degbuf[row] = na; invbuf[row] = inv; }

  for (int k = tid; k < F4; k += 256) {
    f32x4 t = Xi4[k];
    #pragma unroll
    for (int w = 0; w < 4; ++w) t += wsum[w][k];
    us4 o;
    #pragma unroll
    for (int s = 0; s < 4; ++s) o[s] = f32_bf16(t[s] * inv);
    *(us4*)(Xcat + (size_t)row * KS1 + 640 + k * 4) = o;
  }
}

// ---------------------------------------------------------------------------
// gather2: t2 = (h_i + sum_j h_j) * inv. Conflict-free hsum layout
// [g][t][slot] (stride-1 lanes on both write and combine-read; old
// [g][slot*8+t] was 8-way bank conflicted: 3.9M SQ_LDS_BANK_CONFLICT).
// XCD swizzle for hcat batch locality.
// ---------------------------------------------------------------------------
__global__ __launch_bounds__(256) void gather2(
    u16* __restrict__ hcat,          // [ROWS][KS2] bf16
    const u16* __restrict__ nbr,
    const int* __restrict__ degbuf,
    const float* __restrict__ invbuf)
{
  __shared__ u16 accj[512];
  __shared__ float hsum[2][8][120];

  const int tid = threadIdx.x;
  const int row = swiz_row(blockIdx.x);
  const int b = row >> 9;
  const int na = degbuf[row];
  const float inv = invbuf[row];
  for (int c = tid; c < na; c += 256) accj[c] = nbr[(size_t)row * 512 + c];
  __syncthreads();

  const int g = tid >> 7;            // group 0/1
  const int slot = tid & 127;        // us8 slot (8 cols), active < 120
  const u16* hbat = hcat + (size_t)b * NN * KS2;

  float s[8] = {0,0,0,0,0,0,0,0};
  if (slot < 120) {
    for (int c = g; c < na; c += 2) {
      const us8 hv = *(const us8*)(hbat + (size_t)accj[c] * KS2 + slot * 8);
      #pragma unroll
      for (int t = 0; t < 8; ++t) s[t] += bf16_f32(hv[t]);
    }
    #pragma unroll
    for (int t = 0; t < 8; ++t) hsum[g][t][slot] = s[t];
  }
  __syncthreads();

  // zero h pad cols 937..959 (read side discarded everywhere downstream)
  if (tid < 23) hcat[(size_t)row * KS2 + FH + tid] = 0;

  const u16* hrow = hcat + (size_t)row * KS2;
  for (int k = tid; k < 120; k += 256) {     // threads 0..119
    const us8 hv = *(const us8*)(hrow + k * 8);
    us8 o;
    #pragma unroll
    for (int t = 0; t < 8; ++t) {
      const int col = k * 8 + t;
      float v = (bf16_f32(hv[t]) + hsum[0][t][k] + hsum[1][t][k]) * inv;
      o[t] = (col < FH) ? f32_bf16(v) : (u16)0;
    }
    *(us8*)(hcat + (size_t)row * KS2 + 960 + k * 8) = o;
  }
}

// ---------------------------------------------------------------------------
// Weight converters (unchanged).
// ---------------------------------------------------------------------------
__global__ __launch_bounds__(256) void convert_w1(const float* __restrict__ W1,
                                                  u16* __restrict__ Wt) {
  __shared__ float tile[32][33];
  const int kt = blockIdx.x, nt = blockIdx.y;
  const int tx = threadIdx.x & 31, ty = threadIdx.x >> 5;
  #pragma unroll
  for (int r = 0; r < 4; ++r) {
    int k = kt * 32 + ty + r * 8;
    int n = nt * 32 + tx;
    float v = 0.f;
    int c = -1, kk = 0;
    if (k < 625) { c = 0; kk = k; }
    else if (k >= 640 && k < 1265) { c = 1; kk = k - 640; }
    if (c >= 0 && n < FH) v = W1[((size_t)c * 625 + kk) * FH + n];
    tile[ty + r * 8][tx] = v;
  }
  __syncthreads();
  #pragma unroll
  for (int r = 0; r < 4; ++r) {
    int n = nt * 32 + ty + r * 8;
    int k = kt * 32 + tx;
    Wt[(size_t)n * KS1 + k] = f32_bf16(tile[tx][ty + r * 8]);
  }
}

__global__ __launch_bounds__(256) void convert_w2(const float* __restrict__ W2,
                                                  u16* __restrict__ Wt) {
  __shared__ float tile[32][33];
  const int kt = blockIdx.x, nt = blockIdx.y;
  const int tx = threadIdx.x & 31, ty = threadIdx.x >> 5;
  #pragma unroll
  for (int r = 0; r < 4; ++r) {
    int k = kt * 32 + ty + r * 8;
    int n = nt * 32 + tx;
    float v = 0.f;
    int c = -1, kk = 0;
    if (k < 937) { c = 0; kk = k; }
    else if (k >= 960 && k < 1897) { c = 1; kk = k - 960; }
    if (c >= 0 && n < FF) v = W2[((size_t)c * 937 + kk) * FF + n];
    tile[ty + r * 8][tx] = v;
  }
  __syncthreads();
  #pragma unroll
  for (int r = 0; r < 4; ++r) {
    int n = nt * 32 + ty + r * 8;
    int k = kt * 32 + tx;
    Wt[(size_t)n * KS2 + k] = f32_bf16(tile[tx][ty + r * 8]);
  }
}

// ---------------------------------------------------------------------------
// m97-style bf16 GEMM (R2 version): A [M][KS], Bt [Npad][KS], 128x128 tile.
// ---------------------------------------------------------------------------
template <int KS, int NREAL, int LDC, bool OUT_BF16>
__global__ __launch_bounds__(256) void gemm_bt(
    const u16* __restrict__ A, const u16* __restrict__ Bt,
    const float* __restrict__ bias, void* __restrict__ C)
{
  __shared__ __align__(16) u16 Ash[128 * 32];
  __shared__ __align__(16) u16 Bsh[128 * 32];

  const int tid  = threadIdx.x;
  const int lane = tid & 63;
  const int wave = tid >> 6;
  const int wm = wave & 1, wn = wave >> 1;
  const int q = lane >> 4, l16 = lane & 15;
  const int m0 = blockIdx.x * 128;
  const int n0 = blockIdx.y * 128;

  const int i0 = tid, i1 = 256 + tid;
  const u16* pa0 = A + (size_t)(m0 + (i0 >> 2)) * KS + (i0 & 3) * 8;
  const u16* pa1 = A + (size_t)(m0 + (i1 >> 2)) * KS + (i1 & 3) * 8;
  const u16* pb0 = Bt + (size_t)(n0 + (i0 >> 2)) * KS + (i0 & 3) * 8;
  const u16* pb1 = Bt + (size_t)(n0 + (i1 >> 2)) * KS + (i1 & 3) * 8;
  const int wbase = (tid & 192) * 8;
  u16* la0 = &Ash[wbase];       u16* la1 = &Ash[2048 + wbase];
  u16* lb0 = &Bsh[wbase];       u16* lb1 = &Bsh[2048 + wbase];

  const frag_ab* fA[4]; const frag_ab* fB[4];
  #pragma unroll
  for (int mi = 0; mi < 4; ++mi)
    fA[mi] = (const frag_ab*)&Ash[(wm * 64 + mi * 16 + l16) * 32 + q * 8];
  #pragma unroll
  for (int ni = 0; ni < 4; ++ni)
    fB[ni] = (const frag_ab*)&Bsh[(wn * 64 + ni * 16 + l16) * 32 + q * 8];

  frag_cd acc[4][4] = {};

  constexpr int KT = KS / 32;
  for (int kt = 0; kt < KT; ++kt) {
    __syncthreads();
    gload_lds16(pa0, la0); gload_lds16(pa1, la1);
    gload_lds16(pb0, lb0); gload_lds16(pb1, lb1);
    pa0 += 32; pa1 += 32; pb0 += 32; pb1 += 32;
    __syncthreads();

    frag_ab av[4], bv[4];
    #pragma unroll
    for (int mi = 0; mi < 4; ++mi) av[mi] = *fA[mi];
    #pragma unroll
    for (int ni = 0; ni < 4; ++ni) bv[ni] = *fB[ni];
    #pragma unroll
    for (int mi = 0; mi < 4; ++mi)
      #pragma unroll
      for (int ni = 0; ni < 4; ++ni)
        acc[mi][ni] = __builtin_amdgcn_mfma_f32_16x16x32_bf16(
            av[mi], bv[ni], acc[mi][ni], 0, 0, 0);
  }

  #pragma unroll
  for (int ni = 0; ni < 4; ++ni) {
    const int col = n0 + wn * 64 + ni * 16 + l16;
    const bool ok = (col < NREAL);
    const float bvv = ok ? bias[col] : 0.f;
    #pragma unroll
    for (int mi = 0; mi < 4; ++mi) {
      #pragma unroll
      for (int r = 0; r < 4; ++r) {
        const int rowg = m0 + wm * 64 + mi * 16 + q * 4 + r;
        float v = acc[mi][ni][r] + bvv;
        v = fmaxf(v, 0.f);
        if (ok) {
          if (OUT_BF16)
            ((u16*)C)[(size_t)rowg * LDC + col] = f32_bf16(v);
          else
            ((float*)C)[(size_t)rowg * LDC + col] = v;
        }
      }
    }
  }
}

// ---------------------------------------------------------------------------
extern "C" void kernel_launch(void* const* d_in, const int* in_sizes, int n_in,
                              void* d_out, int out_size, void* d_ws, size_t ws_size,
                              hipStream_t stream) {
  const float* x4  = (const float*)d_in[0];
  const float* att = (const float*)d_in[1];
  const float* W1  = (const float*)d_in[2];
  const float* b1  = (const float*)d_in[3];
  const float* W2  = (const float*)d_in[4];
  const float* b2  = (const float*)d_in[5];
  float* out = (float*)d_out;

  char* ws = (char*)d_ws;
  f32x4* Xpad = (f32x4*)ws; ws += (size_t)ROWS * F4 * 16;
  u16* Xcat = (u16*)ws;  ws += (size_t)ROWS * KS1 * 2;
  u16* hcat = (u16*)ws;  ws += (size_t)ROWS * KS2 * 2;
  u16* W1t  = (u16*)ws;  ws += (size_t)NP1 * KS1 * 2;
  u16* W2t  = (u16*)ws;  ws += (size_t)NP2 * KS2 * 2;
  u16* nbr  = (u16*)ws;  ws += (size_t)ROWS * 512 * 2;
  int*   deg = (int*)ws;   ws += (size_t)ROWS * 4;
  float* inv = (float*)ws; ws += (size_t)ROWS * 4;

  convert_w1<<<dim3(KS1 / 32, NP1 / 32), 256, 0, stream>>>(W1, W1t);
  convert_w2<<<dim3(KS2 / 32, NP2 / 32), 256, 0, stream>>>(W2, W2t);
  pad_x<<<dim3((ROWS * F4 + 255) / 256), 256, 0, stream>>>(x4, Xpad, Xcat);
  build_graph<<<dim3(ROWS), 256, 0, stream>>>(Xpad, att, Xcat, nbr, deg, inv);
  gemm_bt<KS1, FH, KS2, true><<<dim3(64, NP1 / 128), 256, 0, stream>>>(
      Xcat, W1t, b1, (void*)hcat);
  gather2<<<dim3(ROWS), 256, 0, stream>>>(hcat, nbr, deg, inv);
  gemm_bt<KS2, FF, FF, false><<<dim3(64, NP2 / 128), 256, 0, stream>>>(
      hcat, W2t, b2, (void*)out);
}

// Round 5
// 244.349 us; speedup vs baseline: 1.2152x; 1.0584x over previous
//
#include <hip/hip_runtime.h>
#include <stdint.h>

typedef uint16_t u16;
typedef __attribute__((ext_vector_type(4))) float f32x4;
typedef __attribute__((ext_vector_type(4))) unsigned short us4;
typedef __attribute__((ext_vector_type(8))) unsigned short us8;

#define NB   16
#define NN   512
#define FF   625      // H*W
#define FH   937      // int(625*1.5)
#define ROWS 8192     // NB*NN
#define KS1  1280     // [X(625) pad->640 | t1(625) pad->640]
#define KS2  1920     // [h(937) pad->960 | t2(937) pad->960]
#define NP1  1024     // Fh padded to 128
#define NP2  640      // F padded to 128
#define F4   160      // 640/4 float4 slots per padded X row

using frag_ab = __attribute__((ext_vector_type(8))) short;  // 8 bf16
using frag_cd = __attribute__((ext_vector_type(4))) float;  // 4 fp32

__device__ __forceinline__ u16 f32_bf16(float f) {
  union { float f; uint32_t u; } x; x.f = f;
  uint32_t r = x.u + 0x7fffu + ((x.u >> 16) & 1u);   // RNE
  return (u16)(r >> 16);
}
__device__ __forceinline__ float bf16_f32(u16 u) {
  union { uint32_t u; float f; } x; x.u = ((uint32_t)u) << 16;
  return x.f;
}
__device__ __forceinline__ void gload_lds16(const void* g, void* l) {
  __builtin_amdgcn_global_load_lds((__attribute__((address_space(1))) void*)g,
                                   (__attribute__((address_space(3))) void*)l,
                                   16, 0, 0);
}
// XCD-aware row swizzle: XCD k handles rows [k*1024, (k+1)*1024) = 2 batches,
// so each XCD's L2 holds only its own batches' working set (R4: 8x FETCH cut).
__device__ __forceinline__ int swiz_row(int blk) {
  return ((blk & 7) << 10) | (blk >> 3);
}

// ---------------------------------------------------------------------------
// prep (fused pad_x + convert_w1 + convert_w2, one launch):
//   blocks [0, 5120)        : pad_x   — x4 -> Xpad f32x4 + Xcat bf16 lo-half
//   blocks [5120, 6400)     : W1 -> W1t bf16 [NP1][KS1]
//   blocks [6400, 7600)     : W2 -> W2t bf16 [NP2][KS2]
// ---------------------------------------------------------------------------
__global__ __launch_bounds__(256) void prep(
    const float* __restrict__ x4, const float* __restrict__ W1,
    const float* __restrict__ W2, f32x4* __restrict__ Xpad,
    u16* __restrict__ Xcat, u16* __restrict__ W1t, u16* __restrict__ W2t)
{
  const int blk = blockIdx.x;
  if (blk < 5120) {
    const int idx = blk * 256 + threadIdx.x;
    if (idx >= ROWS * F4) return;
    const int row = idx / F4;
    const int k4 = idx - row * F4;
    f32x4 v; us4 o;
    #pragma unroll
    for (int t = 0; t < 4; ++t) {
      const int f = k4 * 4 + t;
      float x = (f < FF) ? x4[(size_t)row * FF + f] : 0.f;
      v[t] = x; o[t] = f32_bf16(x);
    }
    Xpad[idx] = v;
    *(us4*)(Xcat + (size_t)row * KS1 + k4 * 4) = o;
  } else if (blk < 6400) {
    __shared__ float tile[32][33];
    const int bb = blk - 5120;            // kt-major: 40 kt x 32 nt
    const int kt = bb % 40, nt = bb / 40;
    const int tx = threadIdx.x & 31, ty = threadIdx.x >> 5;
    #pragma unroll
    for (int r = 0; r < 4; ++r) {
      int k = kt * 32 + ty + r * 8;
      int n = nt * 32 + tx;
      float v = 0.f;
      int c = -1, kk = 0;
      if (k < 625) { c = 0; kk = k; }
      else if (k >= 640 && k < 1265) { c = 1; kk = k - 640; }
      if (c >= 0 && n < FH) v = W1[((size_t)c * 625 + kk) * FH + n];
      tile[ty + r * 8][tx] = v;
    }
    __syncthreads();
    #pragma unroll
    for (int r = 0; r < 4; ++r) {
      int n = nt * 32 + ty + r * 8;
      int k = kt * 32 + tx;
      W1t[(size_t)n * KS1 + k] = f32_bf16(tile[tx][ty + r * 8]);
    }
  } else {
    __shared__ float tile[32][33];
    const int bb = blk - 6400;            // 60 kt x 20 nt
    const int kt = bb % 60, nt = bb / 60;
    const int tx = threadIdx.x & 31, ty = threadIdx.x >> 5;
    #pragma unroll
    for (int r = 0; r < 4; ++r) {
      int k = kt * 32 + ty + r * 8;
      int n = nt * 32 + tx;
      float v = 0.f;
      int c = -1, kk = 0;
      if (k < 937) { c = 0; kk = k; }
      else if (k >= 960 && k < 1897) { c = 1; kk = k - 960; }
      if (c >= 0 && n < FF) v = W2[((size_t)c * 937 + kk) * FF + n];
      tile[ty + r * 8][tx] = v;
    }
    __syncthreads();
    #pragma unroll
    for (int r = 0; r < 4; ++r) {
      int n = nt * 32 + ty + r * 8;
      int k = kt * 32 + tx;
      W2t[(size_t)n * KS2 + k] = f32_bf16(tile[tx][ty + r * 8]);
    }
  }
}

// ---------------------------------------------------------------------------
// build_graph (unchanged from R4: 36 VGPR, 59% occ, XCD swizzle).
// ---------------------------------------------------------------------------
__global__ __launch_bounds__(256) void build_graph(
    const f32x4* __restrict__ Xpad,  // [ROWS][160]
    const float* __restrict__ att,   // [ROWS]
    u16* __restrict__ Xcat,          // [ROWS][KS1] bf16 (t1 half written here)
    u16* __restrict__ nbr,           // [ROWS][512]
    int* __restrict__ degbuf,
    float* __restrict__ invbuf)
{
  __shared__ float att_sh[512];
  __shared__ f32x4 Xi4[F4];
  __shared__ u16 cand[512];
  __shared__ u16 accj[512];
  __shared__ f32x4 wsum[4][F4];
  __shared__ int ncand, nacc;

  const int tid = threadIdx.x;
  const int row = swiz_row(blockIdx.x);
  const int b = row >> 9;
  const int i = row & 511;
  const f32x4* Xb4 = Xpad + (size_t)b * NN * F4;

  att_sh[tid]       = att[b * NN + tid];
  att_sh[tid + 256] = att[b * NN + tid + 256];
  if (tid < F4) Xi4[tid] = Xb4[(size_t)i * F4 + tid];
  if (tid == 0) { ncand = 0; nacc = 0; }
  __syncthreads();

  const float ai = att_sh[i];
  for (int j = tid; j < NN; j += 256) {
    if (j != i && fabsf(ai - att_sh[j]) <= 0.05f) {
      int p = atomicAdd(&ncand, 1);
      cand[p] = (u16)j;
    }
  }
  __syncthreads();

  const int lane = tid & 63;
  const int wave = tid >> 6;
  const int nc = ncand;

  const f32x4 zero = {0.f, 0.f, 0.f, 0.f};
  f32x4 a0 = Xi4[lane];
  f32x4 a1 = Xi4[64 + lane];
  f32x4 a2 = (lane < 32) ? Xi4[128 + lane] : zero;
  f32x4 s0 = zero, s1 = zero, s2 = zero;

  for (int c = wave; c < nc; c += 4) {
    const int j = cand[c];
    const f32x4* Xj = Xb4 + (size_t)j * F4;
    f32x4 x0 = Xj[lane];
    f32x4 x1 = Xj[64 + lane];
    f32x4 x2 = (lane < 32) ? Xj[128 + lane] : zero;
    f32x4 d0 = a0 - x0, d1 = a1 - x1, d2 = a2 - x2;
    float p = 0.f;
    #pragma unroll
    for (int t = 0; t < 4; ++t)
      p += fabsf(d0[t]) + fabsf(d1[t]) + fabsf(d2[t]);
    #pragma unroll
    for (int off = 32; off; off >>= 1) p += __shfl_xor(p, off, 64);
    if (p <= 180.0f) {                       // wave-uniform after butterfly
      s0 += x0; s1 += x1; s2 += x2;
      if (lane == 0) { int q = atomicAdd(&nacc, 1); accj[q] = (u16)j; }
    }
  }
  wsum[wave][lane] = s0;
  wsum[wave][64 + lane] = s1;
  if (lane < 32) wsum[wave][128 + lane] = s2;
  __syncthreads();

  const int na = nacc;
  const float inv = 1.0f / (float)(na + 1);
  for (int c = tid; c < na; c += 256) nbr[(size_t)row * 512 + c] = accj[c];
  if (tid == 0) { degbuf[row] = na; invbuf[row] = inv; }

  for (int k = tid; k < F4; k += 256) {
    f32x4 t = Xi4[k];
    #pragma unroll
    for (int w = 0; w < 4; ++w) t += wsum[w][k];
    us4 o;
    #pragma unroll
    for (int s = 0; s < 4; ++s) o[s] = f32_bf16(t[s] * inv);
    *(us4*)(Xcat + (size_t)row * KS1 + 640 + k * 4) = o;
  }
}

// ---------------------------------------------------------------------------
// gather2 (unchanged from R4): conflict-free hsum, XCD swizzle.
// ---------------------------------------------------------------------------
__global__ __launch_bounds__(256) void gather2(
    u16* __restrict__ hcat,          // [ROWS][KS2] bf16
    const u16* __restrict__ nbr,
    const int* __restrict__ degbuf,
    const float* __restrict__ invbuf)
{
  __shared__ u16 accj[512];
  __shared__ float hsum[2][8][120];

  const int tid = threadIdx.x;
  const int row = swiz_row(blockIdx.x);
  const int b = row >> 9;
  const int na = degbuf[row];
  const float inv = invbuf[row];
  for (int c = tid; c < na; c += 256) accj[c] = nbr[(size_t)row * 512 + c];
  __syncthreads();

  const int g = tid >> 7;
  const int slot = tid & 127;
  const u16* hbat = hcat + (size_t)b * NN * KS2;

  float s[8] = {0,0,0,0,0,0,0,0};
  if (slot < 120) {
    for (int c = g; c < na; c += 2) {
      const us8 hv = *(const us8*)(hbat + (size_t)accj[c] * KS2 + slot * 8);
      #pragma unroll
      for (int t = 0; t < 8; ++t) s[t] += bf16_f32(hv[t]);
    }
    #pragma unroll
    for (int t = 0; t < 8; ++t) hsum[g][t][slot] = s[t];
  }
  __syncthreads();

  if (tid < 23) hcat[(size_t)row * KS2 + FH + tid] = 0;

  const u16* hrow = hcat + (size_t)row * KS2;
  for (int k = tid; k < 120; k += 256) {
    const us8 hv = *(const us8*)(hrow + k * 8);
    us8 o;
    #pragma unroll
    for (int t = 0; t < 8; ++t) {
      const int col = k * 8 + t;
      float v = (bf16_f32(hv[t]) + hsum[0][t][k] + hsum[1][t][k]) * inv;
      o[t] = (col < FH) ? f32_bf16(v) : (u16)0;
    }
    *(us8*)(hcat + (size_t)row * KS2 + 960 + k * 8) = o;
  }
}

// ---------------------------------------------------------------------------
// gemm_bt64: 128x128 tile, BK=64, XOR chunk swizzle.
// LDS layout forced by global_load_lds (lane-order). We swizzle the GLOBAL
// source chunk instead: LDS chunk (row, cpos) holds global k-chunk
// cpos^(row&7). Frag reads address chunk c^(row&7) -> the 8 chunk positions
// spread over all 32 banks (BK=32 row-major put 16 lanes on 8 banks).
// 32 MFMA per barrier pair (2x vs BK=32). 32 KB LDS.
// ---------------------------------------------------------------------------
template <int KS, int NREAL, int LDC, bool OUT_BF16>
__global__ __launch_bounds__(256) void gemm_bt64(
    const u16* __restrict__ A, const u16* __restrict__ Bt,
    const float* __restrict__ bias, void* __restrict__ C)
{
  __shared__ __align__(16) u16 Ash[128 * 64];   // 16 KB
  __shared__ __align__(16) u16 Bsh[128 * 64];   // 16 KB

  const int tid  = threadIdx.x;
  const int lane = tid & 63;
  const int wave = tid >> 6;
  const int wm = wave & 1, wn = wave >> 1;
  const int q = lane >> 4, l16 = lane & 15;
  const int m0 = blockIdx.x * 128;
  const int n0 = blockIdx.y * 128;

  // staging: 4 rounds/matrix; chunk ci = r*256+tid; row=ci>>3, cpos=ci&7;
  // global chunk = cpos ^ (row&7)
  const u16* pa[4]; const u16* pb[4];
  #pragma unroll
  for (int r = 0; r < 4; ++r) {
    const int ci = r * 256 + tid;
    const int row = ci >> 3, cpos = ci & 7;
    const int csrc = cpos ^ (row & 7);
    pa[r] = A  + (size_t)(m0 + row) * KS + csrc * 8;
    pb[r] = Bt + (size_t)(n0 + row) * KS + csrc * 8;
  }
  const int wbase = (tid & 192) * 8;   // elems; + r*2048 per round

  // frag pointers: element (row, kk + q*8): chunk c = q + (kk?4:0), pos = c^(row&7)
  const frag_ab* fA[4][2]; const frag_ab* fB[4][2];
  #pragma unroll
  for (int mi = 0; mi < 4; ++mi) {
    const int row = wm * 64 + mi * 16 + l16;
    fA[mi][0] = (const frag_ab*)&Ash[row * 64 + ((q    ) ^ (l16 & 7)) * 8];
    fA[mi][1] = (const frag_ab*)&Ash[row * 64 + ((q + 4) ^ (l16 & 7)) * 8];
  }
  #pragma unroll
  for (int ni = 0; ni < 4; ++ni) {
    const int row = wn * 64 + ni * 16 + l16;
    fB[ni][0] = (const frag_ab*)&Bsh[row * 64 + ((q    ) ^ (l16 & 7)) * 8];
    fB[ni][1] = (const frag_ab*)&Bsh[row * 64 + ((q + 4) ^ (l16 & 7)) * 8];
  }

  frag_cd acc[4][4] = {};

  constexpr int KT = KS / 64;
  for (int kt = 0; kt < KT; ++kt) {
    __syncthreads();
    #pragma unroll
    for (int r = 0; r < 4; ++r) {
      gload_lds16(pa[r], &Ash[r * 2048 + wbase]);
      gload_lds16(pb[r], &Bsh[r * 2048 + wbase]);
      pa[r] += 64; pb[r] += 64;
    }
    __syncthreads();

    #pragma unroll
    for (int kk = 0; kk < 2; ++kk) {
      frag_ab av[4], bv[4];
      #pragma unroll
      for (int mi = 0; mi < 4; ++mi) av[mi] = *fA[mi][kk];
      #pragma unroll
      for (int ni = 0; ni < 4; ++ni) bv[ni] = *fB[ni][kk];
      #pragma unroll
      for (int mi = 0; mi < 4; ++mi)
        #pragma unroll
        for (int ni = 0; ni < 4; ++ni)
          acc[mi][ni] = __builtin_amdgcn_mfma_f32_16x16x32_bf16(
              av[mi], bv[ni], acc[mi][ni], 0, 0, 0);
    }
  }

  // epilogue: C/D layout col=lane&15, row=(lane>>4)*4+reg
  #pragma unroll
  for (int ni = 0; ni < 4; ++ni) {
    const int col = n0 + wn * 64 + ni * 16 + l16;
    const bool ok = (col < NREAL);
    const float bvv = ok ? bias[col] : 0.f;
    #pragma unroll
    for (int mi = 0; mi < 4; ++mi) {
      #pragma unroll
      for (int r = 0; r < 4; ++r) {
        const int rowg = m0 + wm * 64 + mi * 16 + q * 4 + r;
        float v = acc[mi][ni][r] + bvv;
        v = fmaxf(v, 0.f);
        if (ok) {
          if (OUT_BF16)
            ((u16*)C)[(size_t)rowg * LDC + col] = f32_bf16(v);
          else
            ((float*)C)[(size_t)rowg * LDC + col] = v;
        }
      }
    }
  }
}

// ---------------------------------------------------------------------------
extern "C" void kernel_launch(void* const* d_in, const int* in_sizes, int n_in,
                              void* d_out, int out_size, void* d_ws, size_t ws_size,
                              hipStream_t stream) {
  const float* x4  = (const float*)d_in[0];
  const float* att = (const float*)d_in[1];
  const float* W1  = (const float*)d_in[2];
  const float* b1  = (const float*)d_in[3];
  const float* W2  = (const float*)d_in[4];
  const float* b2  = (const float*)d_in[5];
  float* out = (float*)d_out;

  char* ws = (char*)d_ws;
  f32x4* Xpad = (f32x4*)ws; ws += (size_t)ROWS * F4 * 16;
  u16* Xcat = (u16*)ws;  ws += (size_t)ROWS * KS1 * 2;
  u16* hcat = (u16*)ws;  ws += (size_t)ROWS * KS2 * 2;
  u16* W1t  = (u16*)ws;  ws += (size_t)NP1 * KS1 * 2;
  u16* W2t  = (u16*)ws;  ws += (size_t)NP2 * KS2 * 2;
  u16* nbr  = (u16*)ws;  ws += (size_t)ROWS * 512 * 2;
  int*   deg = (int*)ws;   ws += (size_t)ROWS * 4;
  float* inv = (float*)ws; ws += (size_t)ROWS * 4;

  prep<<<dim3(7600), 256, 0, stream>>>(x4, W1, W2, Xpad, Xcat, W1t, W2t);
  build_graph<<<dim3(ROWS), 256, 0, stream>>>(Xpad, att, Xcat, nbr, deg, inv);
  gemm_bt64<KS1, FH, KS2, true><<<dim3(64, NP1 / 128), 256, 0, stream>>>(
      Xcat, W1t, b1, (void*)hcat);
  gather2<<<dim3(ROWS), 256, 0, stream>>>(hcat, nbr, deg, inv);
  gemm_bt64<KS2, FF, FF, false><<<dim3(64, NP2 / 128), 256, 0, stream>>>(
      hcat, W2t, b2, (void*)out);
}

// Round 6
// 241.229 us; speedup vs baseline: 1.2309x; 1.0129x over previous
//
#include <hip/hip_runtime.h>
#include <stdint.h>

typedef uint16_t u16;
typedef __attribute__((ext_vector_type(4))) float f32x4;
typedef __attribute__((ext_vector_type(4))) unsigned short us4;
typedef __attribute__((ext_vector_type(8))) unsigned short us8;

#define NB   16
#define NN   512
#define FF   625      // H*W
#define FH   937      // int(625*1.5)
#define ROWS 8192     // NB*NN
#define KS1  1280     // [X(625) pad->640 | t1(625) pad->640]
#define KS2  1920     // [h(937) pad->960 | t2(937) pad->960]
#define NP1  1024     // Fh padded to 128
#define NP2  640      // F padded to 128
#define F4   160      // 640/4 float4 slots per padded X row

using frag_ab = __attribute__((ext_vector_type(8))) short;  // 8 bf16
using frag_cd = __attribute__((ext_vector_type(4))) float;  // 4 fp32

__device__ __forceinline__ u16 f32_bf16(float f) {
  union { float f; uint32_t u; } x; x.f = f;
  uint32_t r = x.u + 0x7fffu + ((x.u >> 16) & 1u);   // RNE
  return (u16)(r >> 16);
}
__device__ __forceinline__ float bf16_f32(u16 u) {
  union { uint32_t u; float f; } x; x.u = ((uint32_t)u) << 16;
  return x.f;
}
__device__ __forceinline__ void gload_lds16(const void* g, void* l) {
  __builtin_amdgcn_global_load_lds((__attribute__((address_space(1))) void*)g,
                                   (__attribute__((address_space(3))) void*)l,
                                   16, 0, 0);
}
// XCD-aware row swizzle: XCD k (= blk%8) handles rows [k*1024,(k+1)*1024)
// = batches 2k,2k+1 -> each XCD's L2 holds only its own batches (R4: 8x FETCH cut).
__device__ __forceinline__ int swiz_row(int blk) {
  return ((blk & 7) << 10) | (blk >> 3);
}

// ---------------------------------------------------------------------------
// prep (fused pad_x + convert_w1 + convert_w2).
// ---------------------------------------------------------------------------
__global__ __launch_bounds__(256) void prep(
    const float* __restrict__ x4, const float* __restrict__ W1,
    const float* __restrict__ W2, f32x4* __restrict__ Xpad,
    u16* __restrict__ Xcat, u16* __restrict__ W1t, u16* __restrict__ W2t)
{
  const int blk = blockIdx.x;
  if (blk < 5120) {
    const int idx = blk * 256 + threadIdx.x;
    if (idx >= ROWS * F4) return;
    const int row = idx / F4;
    const int k4 = idx - row * F4;
    f32x4 v; us4 o;
    #pragma unroll
    for (int t = 0; t < 4; ++t) {
      const int f = k4 * 4 + t;
      float x = (f < FF) ? x4[(size_t)row * FF + f] : 0.f;
      v[t] = x; o[t] = f32_bf16(x);
    }
    Xpad[idx] = v;
    *(us4*)(Xcat + (size_t)row * KS1 + k4 * 4) = o;
  } else if (blk < 6400) {
    __shared__ float tile[32][33];
    const int bb = blk - 5120;            // 40 kt x 32 nt
    const int kt = bb % 40, nt = bb / 40;
    const int tx = threadIdx.x & 31, ty = threadIdx.x >> 5;
    #pragma unroll
    for (int r = 0; r < 4; ++r) {
      int k = kt * 32 + ty + r * 8;
      int n = nt * 32 + tx;
      float v = 0.f;
      int c = -1, kk = 0;
      if (k < 625) { c = 0; kk = k; }
      else if (k >= 640 && k < 1265) { c = 1; kk = k - 640; }
      if (c >= 0 && n < FH) v = W1[((size_t)c * 625 + kk) * FH + n];
      tile[ty + r * 8][tx] = v;
    }
    __syncthreads();
    #pragma unroll
    for (int r = 0; r < 4; ++r) {
      int n = nt * 32 + ty + r * 8;
      int k = kt * 32 + tx;
      W1t[(size_t)n * KS1 + k] = f32_bf16(tile[tx][ty + r * 8]);
    }
  } else {
    __shared__ float tile[32][33];
    const int bb = blk - 6400;            // 60 kt x 20 nt
    const int kt = bb % 60, nt = bb / 60;
    const int tx = threadIdx.x & 31, ty = threadIdx.x >> 5;
    #pragma unroll
    for (int r = 0; r < 4; ++r) {
      int k = kt * 32 + ty + r * 8;
      int n = nt * 32 + tx;
      float v = 0.f;
      int c = -1, kk = 0;
      if (k < 937) { c = 0; kk = k; }
      else if (k >= 960 && k < 1897) { c = 1; kk = k - 960; }
      if (c >= 0 && n < FF) v = W2[((size_t)c * 937 + kk) * FF + n];
      tile[ty + r * 8][tx] = v;
    }
    __syncthreads();
    #pragma unroll
    for (int r = 0; r < 4; ++r) {
      int n = nt * 32 + ty + r * 8;
      int k = kt * 32 + tx;
      W2t[(size_t)n * KS2 + k] = f32_bf16(tile[tx][ty + r * 8]);
    }
  }
}

// ---------------------------------------------------------------------------
// build_graph: R4 structure + 1-deep candidate load pipeline (double-buffered
// x0..x2; ~52 VGPR, stays under the 64-VGPR cliff that sank R3's 4x unroll).
// ---------------------------------------------------------------------------
__global__ __launch_bounds__(256) void build_graph(
    const f32x4* __restrict__ Xpad,  // [ROWS][160]
    const float* __restrict__ att,   // [ROWS]
    u16* __restrict__ Xcat,          // [ROWS][KS1] bf16 (t1 half written here)
    u16* __restrict__ nbr,           // [ROWS][512]
    int* __restrict__ degbuf,
    float* __restrict__ invbuf)
{
  __shared__ float att_sh[512];
  __shared__ f32x4 Xi4[F4];
  __shared__ u16 cand[512];
  __shared__ u16 accj[512];
  __shared__ f32x4 wsum[4][F4];
  __shared__ int ncand, nacc;

  const int tid = threadIdx.x;
  const int row = swiz_row(blockIdx.x);
  const int b = row >> 9;
  const int i = row & 511;
  const f32x4* Xb4 = Xpad + (size_t)b * NN * F4;

  att_sh[tid]       = att[b * NN + tid];
  att_sh[tid + 256] = att[b * NN + tid + 256];
  if (tid < F4) Xi4[tid] = Xb4[(size_t)i * F4 + tid];
  if (tid == 0) { ncand = 0; nacc = 0; }
  __syncthreads();

  const float ai = att_sh[i];
  for (int j = tid; j < NN; j += 256) {
    if (j != i && fabsf(ai - att_sh[j]) <= 0.05f) {
      int p = atomicAdd(&ncand, 1);
      cand[p] = (u16)j;
    }
  }
  __syncthreads();

  const int lane = tid & 63;
  const int wave = tid >> 6;
  const int nc = ncand;

  const f32x4 zero = {0.f, 0.f, 0.f, 0.f};
  const f32x4 a0 = Xi4[lane];
  const f32x4 a1 = Xi4[64 + lane];
  const f32x4 a2 = (lane < 32) ? Xi4[128 + lane] : zero;
  f32x4 s0 = zero, s1 = zero, s2 = zero;

  f32x4 x0 = zero, x1 = zero, x2 = zero;
  if (wave < nc) {
    const f32x4* Xj = Xb4 + (size_t)cand[wave] * F4;
    x0 = Xj[lane]; x1 = Xj[64 + lane]; x2 = (lane < 32) ? Xj[128 + lane] : zero;
  }
  for (int c = wave; c < nc; c += 4) {
    // prefetch next candidate (clamped; dead re-load on last iter is harmless)
    const int cn = (c + 4 < nc) ? c + 4 : c;
    const f32x4* Xn = Xb4 + (size_t)cand[cn] * F4;
    const f32x4 y0 = Xn[lane];
    const f32x4 y1 = Xn[64 + lane];
    const f32x4 y2 = (lane < 32) ? Xn[128 + lane] : zero;

    const f32x4 d0 = a0 - x0, d1 = a1 - x1, d2 = a2 - x2;
    float p = 0.f;
    #pragma unroll
    for (int t = 0; t < 4; ++t)
      p += fabsf(d0[t]) + fabsf(d1[t]) + fabsf(d2[t]);
    #pragma unroll
    for (int off = 32; off; off >>= 1) p += __shfl_xor(p, off, 64);
    if (p <= 180.0f) {                       // wave-uniform after butterfly
      s0 += x0; s1 += x1; s2 += x2;
      if (lane == 0) { int q = atomicAdd(&nacc, 1); accj[q] = cand[c]; }
    }
    x0 = y0; x1 = y1; x2 = y2;
  }
  wsum[wave][lane] = s0;
  wsum[wave][64 + lane] = s1;
  if (lane < 32) wsum[wave][128 + lane] = s2;
  __syncthreads();

  const int na = nacc;
  const float inv = 1.0f / (float)(na + 1);
  for (int c = tid; c < na; c += 256) nbr[(size_t)row * 512 + c] = accj[c];
  if (tid == 0) { degbuf[row] = na; invbuf[row] = inv; }

  for (int k = tid; k < F4; k += 256) {
    f32x4 t = Xi4[k];
    #pragma unroll
    for (int w = 0; w < 4; ++w) t += wsum[w][k];
    us4 o;
    #pragma unroll
    for (int s = 0; s < 4; ++s) o[s] = f32_bf16(t[s] * inv);
    *(us4*)(Xcat + (size_t)row * KS1 + 640 + k * 4) = o;
  }
}

// ---------------------------------------------------------------------------
// gather2 (unchanged from R4).
// ---------------------------------------------------------------------------
__global__ __launch_bounds__(256) void gather2(
    u16* __restrict__ hcat,          // [ROWS][KS2] bf16
    const u16* __restrict__ nbr,
    const int* __restrict__ degbuf,
    const float* __restrict__ invbuf)
{
  __shared__ u16 accj[512];
  __shared__ float hsum[2][8][120];

  const int tid = threadIdx.x;
  const int row = swiz_row(blockIdx.x);
  const int b = row >> 9;
  const int na = degbuf[row];
  const float inv = invbuf[row];
  for (int c = tid; c < na; c += 256) accj[c] = nbr[(size_t)row * 512 + c];
  __syncthreads();

  const int g = tid >> 7;
  const int slot = tid & 127;
  const u16* hbat = hcat + (size_t)b * NN * KS2;

  float s[8] = {0,0,0,0,0,0,0,0};
  if (slot < 120) {
    for (int c = g; c < na; c += 2) {
      const us8 hv = *(const us8*)(hbat + (size_t)accj[c] * KS2 + slot * 8);
      #pragma unroll
      for (int t = 0; t < 8; ++t) s[t] += bf16_f32(hv[t]);
    }
    #pragma unroll
    for (int t = 0; t < 8; ++t) hsum[g][t][slot] = s[t];
  }
  __syncthreads();

  if (tid < 23) hcat[(size_t)row * KS2 + FH + tid] = 0;

  const u16* hrow = hcat + (size_t)row * KS2;
  for (int k = tid; k < 120; k += 256) {
    const us8 hv = *(const us8*)(hrow + k * 8);
    us8 o;
    #pragma unroll
    for (int t = 0; t < 8; ++t) {
      const int col = k * 8 + t;
      float v = (bf16_f32(hv[t]) + hsum[0][t][k] + hsum[1][t][k]) * inv;
      o[t] = (col < FH) ? f32_bf16(v) : (u16)0;
    }
    *(us8*)(hcat + (size_t)row * KS2 + 960 + k * 8) = o;
  }
}

// ---------------------------------------------------------------------------
// gemm_bt64<NTILE>: 128M x NTILE-N tile, BK=64, XOR chunk swizzle (R5), plus
// XCD-aligned m-tile: blocks dispatch round-robin (XCD = lin%8 = x&7 since
// gridX=64); mt = ((x&7)<<3)|(x>>3) puts the m-tile on the XCD whose L2 holds
// those rows (written there by build_graph/gather2 with swiz_row). A-reads
// (~160 MB through cache per GEMM) become XCD-local instead of HBM.
// ---------------------------------------------------------------------------
template <int KS, int NTILE, int NREAL, int LDC, bool OUT_BF16>
__global__ __launch_bounds__(256) void gemm_bt64(
    const u16* __restrict__ A, const u16* __restrict__ Bt,
    const float* __restrict__ bias, void* __restrict__ C)
{
  constexpr int NI = NTILE / 32;        // frags per wave in N (2 waves over N)
  constexpr int BR = NTILE / 32;        // B staging rounds (=NTILE*64/(256*8))
  __shared__ __align__(16) u16 Ash[128 * 64];       // 16 KB
  __shared__ __align__(16) u16 Bsh[NTILE * 64];     // 16 or 8 KB

  const int tid  = threadIdx.x;
  const int lane = tid & 63;
  const int wave = tid >> 6;
  const int wm = wave & 1, wn = wave >> 1;
  const int q = lane >> 4, l16 = lane & 15;
  const int x = blockIdx.x;                       // 0..63
  const int mt = ((x & 7) << 3) | (x >> 3);       // XCD-aligned m-tile
  const int m0 = mt * 128;
  const int n0 = blockIdx.y * NTILE;

  // staging: chunk ci = r*256+tid; row=ci>>3, cpos=ci&7; global chunk = cpos^(row&7)
  const u16* pa[4]; const u16* pb[BR];
  #pragma unroll
  for (int r = 0; r < 4; ++r) {
    const int ci = r * 256 + tid;
    const int row = ci >> 3, cpos = ci & 7;
    pa[r] = A + (size_t)(m0 + row) * KS + (cpos ^ (row & 7)) * 8;
  }
  #pragma unroll
  for (int r = 0; r < BR; ++r) {
    const int ci = r * 256 + tid;
    const int row = ci >> 3, cpos = ci & 7;
    pb[r] = Bt + (size_t)(n0 + row) * KS + (cpos ^ (row & 7)) * 8;
  }
  const int wbase = (tid & 192) * 8;   // elems; + r*2048 per round

  // frag pointers: element (row, kk*... ): chunk c = q + kk*4, pos = c^(row&7)
  const frag_ab* fA[4][2]; const frag_ab* fB[NI][2];
  #pragma unroll
  for (int mi = 0; mi < 4; ++mi) {
    const int row = wm * 64 + mi * 16 + l16;
    fA[mi][0] = (const frag_ab*)&Ash[row * 64 + ((q    ) ^ (l16 & 7)) * 8];
    fA[mi][1] = (const frag_ab*)&Ash[row * 64 + ((q + 4) ^ (l16 & 7)) * 8];
  }
  #pragma unroll
  for (int ni = 0; ni < NI; ++ni) {
    const int row = wn * (NTILE / 2) + ni * 16 + l16;
    fB[ni][0] = (const frag_ab*)&Bsh[row * 64 + ((q    ) ^ (l16 & 7)) * 8];
    fB[ni][1] = (const frag_ab*)&Bsh[row * 64 + ((q + 4) ^ (l16 & 7)) * 8];
  }

  frag_cd acc[4][NI] = {};

  constexpr int KT = KS / 64;
  for (int kt = 0; kt < KT; ++kt) {
    __syncthreads();
    #pragma unroll
    for (int r = 0; r < 4; ++r) {
      gload_lds16(pa[r], &Ash[r * 2048 + wbase]);
      pa[r] += 64;
    }
    #pragma unroll
    for (int r = 0; r < BR; ++r) {
      gload_lds16(pb[r], &Bsh[r * 2048 + wbase]);
      pb[r] += 64;
    }
    __syncthreads();

    #pragma unroll
    for (int kk = 0; kk < 2; ++kk) {
      frag_ab av[4], bv[NI];
      #pragma unroll
      for (int mi = 0; mi < 4; ++mi) av[mi] = *fA[mi][kk];
      #pragma unroll
      for (int ni = 0; ni < NI; ++ni) bv[ni] = *fB[ni][kk];
      #pragma unroll
      for (int mi = 0; mi < 4; ++mi)
        #pragma unroll
        for (int ni = 0; ni < NI; ++ni)
          acc[mi][ni] = __builtin_amdgcn_mfma_f32_16x16x32_bf16(
              av[mi], bv[ni], acc[mi][ni], 0, 0, 0);
    }
  }

  // epilogue: C/D layout col=lane&15, row=(lane>>4)*4+reg
  #pragma unroll
  for (int ni = 0; ni < NI; ++ni) {
    const int col = n0 + wn * (NTILE / 2) + ni * 16 + l16;
    const bool ok = (col < NREAL);
    const float bvv = ok ? bias[col] : 0.f;
    #pragma unroll
    for (int mi = 0; mi < 4; ++mi) {
      #pragma unroll
      for (int r = 0; r < 4; ++r) {
        const int rowg = m0 + wm * 64 + mi * 16 + q * 4 + r;
        float v = acc[mi][ni][r] + bvv;
        v = fmaxf(v, 0.f);
        if (ok) {
          if (OUT_BF16)
            ((u16*)C)[(size_t)rowg * LDC + col] = f32_bf16(v);
          else
            ((float*)C)[(size_t)rowg * LDC + col] = v;
        }
      }
    }
  }
}

// ---------------------------------------------------------------------------
extern "C" void kernel_launch(void* const* d_in, const int* in_sizes, int n_in,
                              void* d_out, int out_size, void* d_ws, size_t ws_size,
                              hipStream_t stream) {
  const float* x4  = (const float*)d_in[0];
  const float* att = (const float*)d_in[1];
  const float* W1  = (const float*)d_in[2];
  const float* b1  = (const float*)d_in[3];
  const float* W2  = (const float*)d_in[4];
  const float* b2  = (const float*)d_in[5];
  float* out = (float*)d_out;

  char* ws = (char*)d_ws;
  f32x4* Xpad = (f32x4*)ws; ws += (size_t)ROWS * F4 * 16;
  u16* Xcat = (u16*)ws;  ws += (size_t)ROWS * KS1 * 2;
  u16* hcat = (u16*)ws;  ws += (size_t)ROWS * KS2 * 2;
  u16* W1t  = (u16*)ws;  ws += (size_t)NP1 * KS1 * 2;
  u16* W2t  = (u16*)ws;  ws += (size_t)NP2 * KS2 * 2;
  u16* nbr  = (u16*)ws;  ws += (size_t)ROWS * 512 * 2;
  int*   deg = (int*)ws;   ws += (size_t)ROWS * 4;
  float* inv = (float*)ws; ws += (size_t)ROWS * 4;

  prep<<<dim3(7600), 256, 0, stream>>>(x4, W1, W2, Xpad, Xcat, W1t, W2t);
  build_graph<<<dim3(ROWS), 256, 0, stream>>>(Xpad, att, Xcat, nbr, deg, inv);
  gemm_bt64<KS1, 128, FH, KS2, true><<<dim3(64, NP1 / 128), 256, 0, stream>>>(
      Xcat, W1t, b1, (void*)hcat);
  gather2<<<dim3(ROWS), 256, 0, stream>>>(hcat, nbr, deg, inv);
  gemm_bt64<KS2, 64, FF, FF, false><<<dim3(64, NP2 / 64), 256, 0, stream>>>(
      hcat, W2t, b2, (void*)out);
}

// Round 7
// 222.231 us; speedup vs baseline: 1.3361x; 1.0855x over previous
//
#include <hip/hip_runtime.h>
#include <stdint.h>

typedef uint16_t u16;
typedef uint32_t u32;
typedef __attribute__((ext_vector_type(4))) float f32x4;
typedef __attribute__((ext_vector_type(4))) unsigned short us4;
typedef __attribute__((ext_vector_type(8))) unsigned short us8;

#define NB   16
#define NN   512
#define FF   625      // H*W
#define FH   937      // int(625*1.5)
#define ROWS 8192     // NB*NN
#define KS1  1280     // [X(625) pad->640 | t1(625) pad->640]
#define KS2  1920     // [h(937) pad->960 | t2(937) pad->960]
#define NPX  640      // padded F   (t1 cols / Xt rows per batch)
#define NPH  960      // padded Fh  (t2 cols / ht rows per batch)
#define F4   160      // 640/4 f32x4 slots per padded X row

using frag_ab = __attribute__((ext_vector_type(8))) short;  // 8 bf16
using frag_cd = __attribute__((ext_vector_type(4))) float;  // 4 fp32

__device__ __forceinline__ u16 f32_bf16(float f) {
  union { float f; uint32_t u; } x; x.f = f;
  uint32_t r = x.u + 0x7fffu + ((x.u >> 16) & 1u);   // RNE
  return (u16)(r >> 16);
}
__device__ __forceinline__ void gload_lds16(const void* g, void* l) {
  __builtin_amdgcn_global_load_lds((__attribute__((address_space(1))) void*)g,
                                   (__attribute__((address_space(3))) void*)l,
                                   16, 0, 0);
}
// XCD-aware row swizzle: XCD k (= blk%8) owns rows [k*1024,(k+1)*1024)
// = batches 2k,2k+1 (R4: 8x FETCH cut).
__device__ __forceinline__ int swiz_row(int blk) {
  return ((blk & 7) << 10) | (blk >> 3);
}

// ---------------------------------------------------------------------------
// prep: fused, XCD-aligned where it matters.
//  [0,4096)      pad_x: x4 -> Xpad f32x4 + Xcat bf16 lo; 2 rows/block, XCD-aligned
//  [4096,9216)   Xt:    x4 -> Xt[b][640][512] bf16 (B^T for spmm1), XCD-aligned
//  [9216,10496)  W1 -> W1t [1024][KS1]
//  [10496,11696) W2 -> W2t [640][KS2]
// ---------------------------------------------------------------------------
__global__ __launch_bounds__(256) void prep(
    const float* __restrict__ x4, const float* __restrict__ W1,
    const float* __restrict__ W2, f32x4* __restrict__ Xpad,
    u16* __restrict__ Xcat, u16* __restrict__ Xt,
    u16* __restrict__ W1t, u16* __restrict__ W2t)
{
  const int blk = blockIdx.x;
  const int tid = threadIdx.x;
  if (blk < 4096) {
    const int xcd = blk & 7, loc = blk >> 3;      // loc 0..511
    const int row0 = xcd * 1024 + loc * 2;
    for (int s = tid; s < 320; s += 256) {
      const int row = row0 + (s >= 160);
      const int k4 = (s >= 160) ? s - 160 : s;
      f32x4 v; us4 o;
      #pragma unroll
      for (int t = 0; t < 4; ++t) {
        const int f = k4 * 4 + t;
        float x = (f < FF) ? x4[(size_t)row * FF + f] : 0.f;
        v[t] = x; o[t] = f32_bf16(x);
      }
      Xpad[(size_t)row * F4 + k4] = v;
      *(us4*)(Xcat + (size_t)row * KS1 + k4 * 4) = o;
    }
  } else if (blk < 9216) {
    __shared__ float tile[32][33];
    const int bb = blk - 4096;
    const int xcd = bb & 7, sub = bb >> 3;        // sub 0..639
    const int b = xcd * 2 + sub / 320;
    const int t = sub % 320;
    const int ft = t % 20, kt = t / 20;           // ft 0..19, kt 0..15
    const int tx = tid & 31, ty = tid >> 5;
    #pragma unroll
    for (int r = 0; r < 4; ++r) {
      const int node = kt * 32 + ty + r * 8;
      const int f = ft * 32 + tx;
      tile[ty + r * 8][tx] = (f < FF) ? x4[((size_t)b * NN + node) * FF + f] : 0.f;
    }
    __syncthreads();
    #pragma unroll
    for (int r = 0; r < 4; ++r) {
      const int f = ft * 32 + ty + r * 8;
      const int node = kt * 32 + tx;
      Xt[((size_t)b * NPX + f) * 512 + node] = f32_bf16(tile[tx][ty + r * 8]);
    }
  } else if (blk < 10496) {
    __shared__ float tile[32][33];
    const int bb = blk - 9216;                    // 40 kt x 32 nt
    const int kt = bb % 40, nt = bb / 40;
    const int tx = tid & 31, ty = tid >> 5;
    #pragma unroll
    for (int r = 0; r < 4; ++r) {
      int k = kt * 32 + ty + r * 8;
      int n = nt * 32 + tx;
      float v = 0.f;
      int c = -1, kk = 0;
      if (k < 625) { c = 0; kk = k; }
      else if (k >= 640 && k < 1265) { c = 1; kk = k - 640; }
      if (c >= 0 && n < FH) v = W1[((size_t)c * 625 + kk) * FH + n];
      tile[ty + r * 8][tx] = v;
    }
    __syncthreads();
    #pragma unroll
    for (int r = 0; r < 4; ++r) {
      int n = nt * 32 + ty + r * 8;
      int k = kt * 32 + tx;
      W1t[(size_t)n * KS1 + k] = f32_bf16(tile[tx][ty + r * 8]);
    }
  } else {
    __shared__ float tile[32][33];
    const int bb = blk - 10496;                   // 60 kt x 20 nt
    const int kt = bb % 60, nt = bb / 60;
    const int tx = tid & 31, ty = tid >> 5;
    #pragma unroll
    for (int r = 0; r < 4; ++r) {
      int k = kt * 32 + ty + r * 8;
      int n = nt * 32 + tx;
      float v = 0.f;
      int c = -1, kk = 0;
      if (k < 937) { c = 0; kk = k; }
      else if (k >= 960 && k < 1897) { c = 1; kk = k - 960; }
      if (c >= 0 && n < FF) v = W2[((size_t)c * 937 + kk) * FF + n];
      tile[ty + r * 8][tx] = v;
    }
    __syncthreads();
    #pragma unroll
    for (int r = 0; r < 4; ++r) {
      int n = nt * 32 + ty + r * 8;
      int k = kt * 32 + tx;
      W2t[(size_t)n * KS2 + k] = f32_bf16(tile[tx][ty + r * 8]);
    }
  }
}

// ---------------------------------------------------------------------------
// build_L: per-row block. att filter -> candidates; 2 candidates per wave
// (32 lanes each, 5 f32x4 slots/lane, 5-step half-wave butterfly — halves the
// serial shfl chain at ZERO extra VGPR, unlike R3/R6 unroll attempts).
// Writes bf16 L row: dinv at accepted j and self, 0 elsewhere. No gather.
// ---------------------------------------------------------------------------
__global__ __launch_bounds__(256) void build_L(
    const f32x4* __restrict__ Xpad,  // [ROWS][160]
    const float* __restrict__ att,   // [ROWS]
    u16* __restrict__ L)             // [NB][512][512] bf16 row-major
{
  __shared__ float att_sh[512];
  __shared__ f32x4 Xi4[F4];
  __shared__ u16 cand[512];
  __shared__ u16 flag[512];
  __shared__ int ncand, nacc;

  const int tid = threadIdx.x;
  const int row = swiz_row(blockIdx.x);
  const int b = row >> 9;
  const int i = row & 511;
  const f32x4* Xb4 = Xpad + (size_t)b * NN * F4;

  att_sh[tid]       = att[b * NN + tid];
  att_sh[tid + 256] = att[b * NN + tid + 256];
  if (tid < F4) Xi4[tid] = Xb4[(size_t)i * F4 + tid];
  flag[tid] = 0; flag[tid + 256] = 0;
  if (tid == 0) { ncand = 0; nacc = 0; }
  __syncthreads();

  const float ai = att_sh[i];
  for (int j = tid; j < NN; j += 256) {
    if (j != i && fabsf(ai - att_sh[j]) <= 0.05f) {
      int p = atomicAdd(&ncand, 1);
      cand[p] = (u16)j;
    }
  }
  __syncthreads();
  if (tid == 0) flag[i] = 1;        // self (A+I diagonal)

  const int hl = tid & 31;          // half-lane
  const int hw = tid >> 5;          // half-wave 0..7
  const int nc = ncand;

  const f32x4 a0 = Xi4[hl];
  const f32x4 a1 = Xi4[32 + hl];
  const f32x4 a2 = Xi4[64 + hl];
  const f32x4 a3 = Xi4[96 + hl];
  const f32x4 a4 = Xi4[128 + hl];

  for (int c = hw; c < nc; c += 8) {
    const int j = cand[c];
    const f32x4* Xj = Xb4 + (size_t)j * F4;
    const f32x4 d0 = a0 - Xj[hl];
    const f32x4 d1 = a1 - Xj[32 + hl];
    const f32x4 d2 = a2 - Xj[64 + hl];
    const f32x4 d3 = a3 - Xj[96 + hl];
    const f32x4 d4 = a4 - Xj[128 + hl];
    float p = 0.f;
    #pragma unroll
    for (int t = 0; t < 4; ++t)
      p += fabsf(d0[t]) + fabsf(d1[t]) + fabsf(d2[t]) + fabsf(d3[t]) + fabsf(d4[t]);
    #pragma unroll
    for (int off = 16; off; off >>= 1) p += __shfl_xor(p, off, 64);  // half-wave
    if (hl == 0 && p <= 180.0f) {
      atomicAdd(&nacc, 1);
      flag[j] = 1;
    }
  }
  __syncthreads();

  const u16 dv = f32_bf16(1.0f / (float)(nacc + 1));
  const u32 lo = flag[2 * tid]     ? (u32)dv : 0u;
  const u32 hi = flag[2 * tid + 1] ? (u32)dv : 0u;
  *(u32*)(L + (size_t)row * 512 + 2 * tid) = lo | (hi << 16);
}

// ---------------------------------------------------------------------------
// gemm_core: 128M x NTILE-N tile, BK=64, XOR chunk swizzle (R5/R6 proven).
// Epilogue: store cols < NSTORE; value = col<NREAL ? f(acc) : 0.
// ---------------------------------------------------------------------------
template <int KS, int NTILE, int NREAL, int NSTORE, bool RELU, bool BIAS, bool OUT_BF16>
__device__ __forceinline__ void gemm_core(
    const u16* __restrict__ At,      // A tile base: rows 0..127, stride KS
    const u16* __restrict__ Btt,     // B^T tile base: rows 0..NTILE-1, stride KS
    const float* __restrict__ bias, void* __restrict__ C,
    long crow0, int col0, int ldc)
{
  constexpr int NI = NTILE / 32;
  constexpr int BR = NTILE / 32;
  __shared__ __align__(16) u16 Ash[128 * 64];
  __shared__ __align__(16) u16 Bsh[NTILE * 64];

  const int tid  = threadIdx.x;
  const int lane = tid & 63;
  const int wave = tid >> 6;
  const int wm = wave & 1, wn = wave >> 1;
  const int q = lane >> 4, l16 = lane & 15;

  const u16* pa[4]; const u16* pb[BR];
  #pragma unroll
  for (int r = 0; r < 4; ++r) {
    const int ci = r * 256 + tid;
    const int row = ci >> 3, cpos = ci & 7;
    pa[r] = At + (size_t)row * KS + (cpos ^ (row & 7)) * 8;
  }
  #pragma unroll
  for (int r = 0; r < BR; ++r) {
    const int ci = r * 256 + tid;
    const int row = ci >> 3, cpos = ci & 7;
    pb[r] = Btt + (size_t)row * KS + (cpos ^ (row & 7)) * 8;
  }
  const int wbase = (tid & 192) * 8;

  const frag_ab* fA[4][2]; const frag_ab* fB[NI][2];
  #pragma unroll
  for (int mi = 0; mi < 4; ++mi) {
    const int row = wm * 64 + mi * 16 + l16;
    fA[mi][0] = (const frag_ab*)&Ash[row * 64 + ((q    ) ^ (l16 & 7)) * 8];
    fA[mi][1] = (const frag_ab*)&Ash[row * 64 + ((q + 4) ^ (l16 & 7)) * 8];
  }
  #pragma unroll
  for (int ni = 0; ni < NI; ++ni) {
    const int row = wn * (NTILE / 2) + ni * 16 + l16;
    fB[ni][0] = (const frag_ab*)&Bsh[row * 64 + ((q    ) ^ (l16 & 7)) * 8];
    fB[ni][1] = (const frag_ab*)&Bsh[row * 64 + ((q + 4) ^ (l16 & 7)) * 8];
  }

  frag_cd acc[4][NI] = {};

  constexpr int KT = KS / 64;
  for (int kt = 0; kt < KT; ++kt) {
    __syncthreads();
    #pragma unroll
    for (int r = 0; r < 4; ++r) { gload_lds16(pa[r], &Ash[r * 2048 + wbase]); pa[r] += 64; }
    #pragma unroll
    for (int r = 0; r < BR; ++r) { gload_lds16(pb[r], &Bsh[r * 2048 + wbase]); pb[r] += 64; }
    __syncthreads();

    #pragma unroll
    for (int kk = 0; kk < 2; ++kk) {
      frag_ab av[4], bv[NI];
      #pragma unroll
      for (int mi = 0; mi < 4; ++mi) av[mi] = *fA[mi][kk];
      #pragma unroll
      for (int ni = 0; ni < NI; ++ni) bv[ni] = *fB[ni][kk];
      #pragma unroll
      for (int mi = 0; mi < 4; ++mi)
        #pragma unroll
        for (int ni = 0; ni < NI; ++ni)
          acc[mi][ni] = __builtin_amdgcn_mfma_f32_16x16x32_bf16(
              av[mi], bv[ni], acc[mi][ni], 0, 0, 0);
    }
  }

  #pragma unroll
  for (int ni = 0; ni < NI; ++ni) {
    const int col = col0 + wn * (NTILE / 2) + ni * 16 + l16;
    if (col >= NSTORE) continue;
    const bool ok = (col < NREAL);
    float bvv = 0.f;
    if (BIAS) bvv = ok ? bias[col] : 0.f;
    #pragma unroll
    for (int mi = 0; mi < 4; ++mi) {
      #pragma unroll
      for (int r = 0; r < 4; ++r) {
        const long rowg = crow0 + wm * 64 + mi * 16 + q * 4 + r;
        float v = acc[mi][ni][r];
        if (BIAS) v += bvv;
        if (RELU) v = fmaxf(v, 0.f);
        if (!ok) v = 0.f;
        if (OUT_BF16) ((u16*)C)[rowg * (size_t)ldc + col] = f32_bf16(v);
        else          ((float*)C)[rowg * (size_t)ldc + col] = v;
      }
    }
  }
}

// dense: grid (64, Nt); XCD-aligned m-tile (R6)
template <int KS, int NTILE, int NREAL, int NSTORE, bool RELU, bool BIAS, bool OUT_BF16>
__global__ __launch_bounds__(256) void gemm_dense(
    const u16* __restrict__ A, const u16* __restrict__ Bt,
    const float* __restrict__ bias, void* __restrict__ C, int ldc)
{
  const int x = blockIdx.x;
  const int mt = ((x & 7) << 3) | (x >> 3);
  gemm_core<KS, NTILE, NREAL, NSTORE, RELU, BIAS, OUT_BF16>(
      A + (size_t)mt * 128 * KS, Bt + (size_t)blockIdx.y * NTILE * KS,
      bias, C, (long)mt * 128, blockIdx.y * NTILE, ldc);
}

// batched spmm: t = L_b · B_b^T; 1D grid 16*TPB, batch b on XCD b/2 (L2-local
// L/Bt/C). NP = padded N (640 or 960), K = 512.
template <int NP>
__global__ __launch_bounds__(256) void spmm(
    const u16* __restrict__ L, const u16* __restrict__ Bt,
    u16* __restrict__ C, int ldc)
{
  constexpr int TPB = 4 * (NP / 64);
  const int blk = blockIdx.x;
  const int xcd = blk & 7, sub = blk >> 3;
  const int b = xcd * 2 + sub / TPB;
  const int t = sub % TPB;
  const int mt = t & 3, nt = t >> 2;
  gemm_core<512, 64, NP, NP, false, false, true>(
      L + ((size_t)b * 512 + mt * 128) * 512,
      Bt + ((size_t)b * NP + nt * 64) * 512,
      nullptr, C, (long)b * 512 + mt * 128, nt * 64, ldc);
}

// ---------------------------------------------------------------------------
// transpose_h: hcat h-half [b][node][0..960) -> ht [b][960][512] bf16.
// ---------------------------------------------------------------------------
__global__ __launch_bounds__(256) void transpose_h(
    const u16* __restrict__ hcat, u16* __restrict__ ht)
{
  __shared__ u16 tile[32][34];
  const int blk = blockIdx.x;                   // 7680
  const int xcd = blk & 7, sub = blk >> 3;      // sub 0..959
  const int b = xcd * 2 + sub / 480;
  const int t = sub % 480;
  const int kt = t % 16, nt = t / 16;           // kt 0..15, nt 0..29
  const int tid = threadIdx.x;
  const int tx = tid & 31, ty = tid >> 5;
  #pragma unroll
  for (int r = 0; r < 4; ++r) {
    const int node = kt * 32 + ty + r * 8;
    const int n = nt * 32 + tx;
    tile[ty + r * 8][tx] = hcat[((size_t)b * NN + node) * KS2 + n];
  }
  __syncthreads();
  #pragma unroll
  for (int r = 0; r < 4; ++r) {
    const int n = nt * 32 + ty + r * 8;
    const int node = kt * 32 + tx;
    ht[((size_t)b * NPH + n) * 512 + node] = tile[tx][ty + r * 8];
  }
}

// ---------------------------------------------------------------------------
extern "C" void kernel_launch(void* const* d_in, const int* in_sizes, int n_in,
                              void* d_out, int out_size, void* d_ws, size_t ws_size,
                              hipStream_t stream) {
  const float* x4  = (const float*)d_in[0];
  const float* att = (const float*)d_in[1];
  const float* W1  = (const float*)d_in[2];
  const float* b1  = (const float*)d_in[3];
  const float* W2  = (const float*)d_in[4];
  const float* b2  = (const float*)d_in[5];
  float* out = (float*)d_out;

  char* ws = (char*)d_ws;
  f32x4* Xpad = (f32x4*)ws;                                 // 20.97 MB
  u16* ht = (u16*)ws;       ws += (size_t)ROWS * F4 * 16;   // ht (15.7 MB) aliases
                                                            // Xpad: dead after build_L
  u16* Xcat = (u16*)ws;  ws += (size_t)ROWS * KS1 * 2;      // 20.97 MB
  u16* hcat = (u16*)ws;  ws += (size_t)ROWS * KS2 * 2;      // 31.46 MB
  u16* W1t  = (u16*)ws;  ws += (size_t)1024 * KS1 * 2;      //  2.62 MB
  u16* W2t  = (u16*)ws;  ws += (size_t)640 * KS2 * 2;       //  2.46 MB
  u16* Lm   = (u16*)ws;  ws += (size_t)NB * 512 * 512 * 2;  //  8.39 MB
  u16* Xt   = (u16*)ws;  ws += (size_t)NB * NPX * 512 * 2;  // 10.49 MB

  prep<<<dim3(11696), 256, 0, stream>>>(x4, W1, W2, Xpad, Xcat, Xt, W1t, W2t);
  build_L<<<dim3(ROWS), 256, 0, stream>>>(Xpad, att, Lm);
  spmm<NPX><<<dim3(640), 256, 0, stream>>>(Lm, Xt, Xcat + NPX, KS1);
  gemm_dense<KS1, 128, FH, NPH, true, true, true><<<dim3(64, 8), 256, 0, stream>>>(
      Xcat, W1t, b1, (void*)hcat, KS2);
  transpose_h<<<dim3(7680), 256, 0, stream>>>(hcat, ht);
  spmm<NPH><<<dim3(960), 256, 0, stream>>>(Lm, ht, hcat + NPH, KS2);
  gemm_dense<KS2, 64, FF, FF, true, true, false><<<dim3(64, 10), 256, 0, stream>>>(
      hcat, W2t, b2, (void*)out, FF);
}